// Round 2
// baseline (106.677 us; speedup 1.0000x reference)
//
#include <hip/hip_runtime.h>

#define BSZ   2
#define NBOX  6300
#define NATTR 85
#define NCLS  80
#define CAP   256   // per-(img,class) capacity; count ~ Binom(6300, 0.00625): mean 39, sd 6.3

// One wave (64 lanes) per box. Lanes cooperatively load the 85 attrs,
// reduce max/argmax over class scores (attrs 5..84) with first-index
// tiebreak (matches jnp.argmax). Writes per-box: raw max class score and
// vcls = (valid ? cls : -1). Also zeroes d_out (first 100800 threads).
// No atomics, no zero-init needed: every slot of bms/vcls is written.
__global__ __launch_bounds__(256) void prep_kernel(
    const float* __restrict__ x,
    float* __restrict__ bms,      // [BSZ*NBOX] raw max class score
    int* __restrict__ vcls,       // [BSZ*NBOX] class if valid else -1
    float* __restrict__ out) {    // [BSZ*NBOX*8] zeroed here
  int gid  = blockIdx.x * blockDim.x + threadIdx.x;
  if (gid < BSZ * NBOX * 8) out[gid] = 0.0f;   // fused output clear

  int wave = gid >> 6;
  int lane = threadIdx.x & 63;
  if (wave >= BSZ * NBOX) return;

  const float* p = x + (long)wave * NATTR;
  float r0 = p[lane];                                    // attrs 0..63
  float r1 = (lane < NATTR - 64) ? p[64 + lane] : -1.0f; // attrs 64..84

  // candidate from this lane: class scores only (attr >= 5)
  float c0 = (lane >= 5) ? r0 : -1.0f;
  float v; int vi;
  if (r1 > c0) { v = r1; vi = 64 + lane; }   // equal -> keep lower index c0
  else         { v = c0; vi = lane; }

  // wave64 reduction: max value, lowest attr index among maxes
  for (int off = 32; off > 0; off >>= 1) {
    float ov = __shfl_down(v, off);
    int   oi = __shfl_down(vi, off);
    if (ov > v || (ov == v && oi < vi)) { v = ov; vi = oi; }
  }

  float obj = __shfl(r0, 4);   // attr 4 = objectness
  if (lane == 0) {
    bms[wave] = v;
    // valid = (obj > CONF) & (max > SCORE); masking doesn't change the compare
    vcls[wave] = (obj > 0.5f && v > 0.3f) ? (vi - 5) : -1;
  }
}

// One single-wave block per (image, class). Greedy NMS restricted to one
// class is exactly equivalent to the reference's global greedy loop
// (suppression requires same_cls; invalid boxes never act).
__global__ __launch_bounds__(64) void nms_kernel(
    const float* __restrict__ x,
    const float* __restrict__ bms,
    const int* __restrict__ vcls,
    float* __restrict__ out) {
  __shared__ float sx1[CAP], sy1[CAP], sx2[CAP], sy2[CAP], ssc[CAP];
  __shared__ int   sbi[CAP];
  __shared__ int   order[CAP];
  __shared__ unsigned char keepS[CAP];

  int bc  = blockIdx.x;
  int img = bc / NCLS;
  int cls = bc - img * NCLS;
  int t   = threadIdx.x;
  const int* v = vcls + img * NBOX;

  // ballot-compaction scan: gather boxes of this class in ascending index
  // order (deterministic; feeds the stable sort's index tiebreak).
  int cnt = 0;
  for (int base = 0; base < NBOX; base += 64) {
    int i = base + t;
    bool match = (i < NBOX) && (v[i] == cls);
    unsigned long long m = __ballot(match);
    if (match) {
      int pos = cnt + __popcll(m & ((1ull << t) - 1ull));
      if (pos < CAP) {
        const float* p = x + ((long)img * NBOX + i) * NATTR;
        float cx = p[0], cy = p[1], w = p[2], h = p[3];
        float hw = w * 0.5f, hh = h * 0.5f;   // exact halving, no contraction hazard
        sx1[pos] = cx - hw; sy1[pos] = cy - hh;
        sx2[pos] = cx + hw; sy2[pos] = cy + hh;
        ssc[pos] = p[4];    sbi[pos] = i;
      }
    }
    cnt += __popcll(m);
  }
  int k = cnt > CAP ? CAP : cnt;
  __syncthreads();
  if (k == 0) return;

  // rank sort by (score desc, original index asc) == stable argsort(-score)
  for (int e = t; e < k; e += 64) {
    float se = ssc[e]; int ie = sbi[e];
    int r = 0;
    for (int j = 0; j < k; j++) {
      float sj = ssc[j];
      r += (sj > se) || (sj == se && sbi[j] < ie);
    }
    order[r] = e;
    keepS[e] = 1;
  }
  __syncthreads();

  // greedy: in score order, a kept box suppresses later same-class boxes
  // with IoU >= 0.4 (exact ref arithmetic, IEEE fp32 div)
  for (int r = 0; r + 1 < k; r++) {
    if (keepS[r]) {                 // uniform LDS broadcast read
      int e = order[r];
      float X1 = sx1[e], Y1 = sy1[e], X2 = sx2[e], Y2 = sy2[e];
      float ar = (X2 - X1) * (Y2 - Y1);
      for (int rr = r + 1 + t; rr < k; rr += 64) {
        int e2 = order[rr];
        float iw = fminf(X2, sx2[e2]) - fmaxf(X1, sx1[e2]);
        float ih = fminf(Y2, sy2[e2]) - fmaxf(Y1, sy1[e2]);
        iw = fmaxf(iw, 0.0f); ih = fmaxf(ih, 0.0f);
        float inter = iw * ih;
        float a2 = (sx2[e2] - sx1[e2]) * (sy2[e2] - sy1[e2]);
        float iou = inter / (ar + a2 - inter + 1e-16f);
        if (iou >= 0.4f) keepS[rr] = 0;
      }
    }
    __syncthreads();   // single-wave block: just an in-wave LDS fence
  }

  // write kept rows: [batch, x1, y1, x2, y2, p_obj, max_score, cls]
  for (int r = t; r < k; r += 64) {
    if (keepS[r]) {
      int e  = order[r];
      long g = (long)img * NBOX + sbi[e];
      float* o = out + g * 8;
      o[0] = (float)img;
      o[1] = sx1[e]; o[2] = sy1[e]; o[3] = sx2[e]; o[4] = sy2[e];
      o[5] = ssc[e];
      o[6] = bms[g];
      o[7] = (float)cls;
    }
  }
}

extern "C" void kernel_launch(void* const* d_in, const int* in_sizes, int n_in,
                              void* d_out, int out_size, void* d_ws, size_t ws_size,
                              hipStream_t stream) {
  const float* x = (const float*)d_in[0];
  float* out = (float*)d_out;

  float* bms = (float*)d_ws;              // 12600 floats
  int* vcls  = (int*)(bms + BSZ * NBOX);  // 12600 ints

  prep_kernel<<<(BSZ * NBOX * 64) / 256, 256, 0, stream>>>(x, bms, vcls, out);
  nms_kernel<<<BSZ * NCLS, 64, 0, stream>>>(x, bms, vcls, out);
}

// Round 3
// 73.454 us; speedup vs baseline: 1.4523x; 1.4523x over previous
//
#include <hip/hip_runtime.h>

#define BSZ   2
#define NBOX  6300
#define NATTR 85
#define NCLS  80
#define CAP   256      // per-(img,class) candidate cap; count ~ Binom(6300,1/160): mean 39, sd 6.3

typedef unsigned long long ull;

static __device__ __forceinline__ ull mask_for(int rem) {
  // bits [0, rem) set, clamped to [0,64]
  if (rem <= 0) return 0ull;
  if (rem >= 64) return ~0ull;
  return (1ull << rem) - 1ull;
}

// One wave per box. Lanes load the 85 attrs, butterfly-reduce max/argmax over
// class scores (attrs 5..84, first-index tiebreak = jnp.argmax). The wave then
// writes its FINAL output row to d_out: the real detection row if valid, zeros
// otherwise (each wave owns its 32-B row -> no races, no separate memset).
// Also writes vcls[box] = valid ? cls : -1 for the nms scan.
__global__ __launch_bounds__(256) void prep_kernel(
    const float* __restrict__ x,
    int* __restrict__ vcls,
    float* __restrict__ out) {
  int gid  = blockIdx.x * blockDim.x + threadIdx.x;
  int box  = gid >> 6;                 // grid is exact: 12600 waves
  int lane = threadIdx.x & 63;

  const float* p = x + (long)box * NATTR;
  float r0 = p[lane];                                    // attrs 0..63
  float r1 = (lane < NATTR - 64) ? p[64 + lane] : -1.0f; // attrs 64..84

  float c0 = (lane >= 5) ? r0 : -1.0f;
  float v; int vi;
  if (r1 > c0) { v = r1; vi = 64 + lane; }   // equal -> keep lower index c0
  else         { v = c0; vi = lane; }

  // butterfly max-argmax: all lanes end with (max, lowest index)
  for (int off = 32; off > 0; off >>= 1) {
    float ov = __shfl_xor(v, off);
    int   oi = __shfl_xor(vi, off);
    if (ov > v || (ov == v && oi < vi)) { v = ov; vi = oi; }
  }

  float cx  = __shfl(r0, 0), cy = __shfl(r0, 1);
  float w   = __shfl(r0, 2), h  = __shfl(r0, 3);
  float obj = __shfl(r0, 4);
  bool valid = (obj > 0.5f) && (v > 0.3f);
  int  img   = box >= NBOX ? 1 : 0;
  int  cls   = vi - 5;

  if (lane == 0) {
    vcls[box] = valid ? cls : -1;
    float4 a, b;
    if (valid) {
      float hw = w * 0.5f, hh = h * 0.5f;   // exact halving; fma-safe
      a = make_float4((float)img, cx - hw, cy - hh, cx + hw);
      b = make_float4(cy + hh, obj, v, (float)cls);
    } else {
      a = make_float4(0.f, 0.f, 0.f, 0.f);
      b = a;
    }
    float4* o = (float4*)(out + (long)box * 8);
    o[0] = a; o[1] = b;
  }
}

// One 256-thread block (4 waves) per (image, class). Per-class greedy NMS is
// exactly equivalent to the reference's global greedy loop (suppression
// requires same_cls; invalid boxes never act). Kept rows are already correct
// in d_out (written by prep); this kernel only ZEROES suppressed rows.
__global__ __launch_bounds__(256) void nms_kernel(
    const int* __restrict__ vcls,
    float* out) {
  __shared__ int   wlist[4][CAP];
  __shared__ int   wcnt[4];
  __shared__ int   sbi[CAP];
  __shared__ float ssc[CAP];
  __shared__ float px1[CAP], py1[CAP], px2[CAP], py2[CAP];
  __shared__ int   pbi[CAP];

  int bc   = blockIdx.x;
  int img  = bc / NCLS;
  int cls  = bc - img * NCLS;
  int t    = threadIdx.x;
  int lane = t & 63;
  int w    = t >> 6;
  const int* v = vcls + img * NBOX;

  // ---- Phase A: parallel class scan (4 waves x 25 iters over 6300) ----
  // all 25 loads issued independently first (one vmcnt drain), then the
  // cheap ballot/popcount chain; ascending-index order preserved.
  int base = w * 1600;                 // 4 * 1600 = 6400 >= 6300
  int vals[25];
#pragma unroll
  for (int i = 0; i < 25; i++) {
    int idx = base + i * 64 + lane;
    vals[i] = (idx < NBOX) ? v[idx] : -1;
  }
  int cnt = 0;
#pragma unroll
  for (int i = 0; i < 25; i++) {
    bool match = (vals[i] == cls);
    ull  m = __ballot(match);
    if (match) {
      int pos = cnt + __popcll(m & ((1ull << lane) - 1ull));
      if (pos < CAP) wlist[w][pos] = base + i * 64 + lane;
    }
    cnt += __popcll(m);
  }
  if (lane == 0) wcnt[w] = cnt < CAP ? cnt : CAP;
  __syncthreads();

  int off = 0, total = 0;
  for (int j = 0; j < 4; j++) {
    int c = wcnt[j];
    if (j < w) off += c;
    total += c;
  }
  int k = total < CAP ? total : CAP;
  if (k == 0) return;                  // uniform across block

  for (int j = lane; j < wcnt[w]; j += 64) {
    int d = off + j;
    if (d < CAP) sbi[d] = wlist[w][j];
  }
  __syncthreads();

  // ---- Phase B: parallel gather of candidate rows from d_out ----
  float bx1 = 0, by1 = 0, bx2 = 0, by2 = 0, bobj = 0;
  int   bidx = 0;
  if (t < k) {
    bidx = sbi[t];
    const float4* o = (const float4*)(out + ((long)img * NBOX + bidx) * 8);
    float4 a = o[0], b = o[1];
    bx1 = a.y; by1 = a.z; bx2 = a.w; by2 = b.x; bobj = b.y;
    ssc[t] = bobj;
  }
  __syncthreads();

  // ---- Phase C1: rank sort (score desc, index asc) == stable argsort ----
  if (t < k) {
    int rank = 0;
    for (int j = 0; j < k; j++) {
      float sj = ssc[j];
      rank += (sj > bobj) || (sj == bobj && sbi[j] < bidx);
    }
    px1[rank] = bx1; py1[rank] = by1;
    px2[rank] = bx2; py2[rank] = by2;
    pbi[rank] = bidx;
  }
  __syncthreads();

  // ---- Phase C2 + D: wave 0 greedy in registers, zero suppressed rows ----
  if (w == 0) {
    float mx1[4], my1[4], mx2[4], my2[4], mar[4];
    int   mbi[4];
#pragma unroll
    for (int s = 0; s < 4; s++) {
      int e = s * 64 + lane;
      if (e < k) {
        mx1[s] = px1[e]; my1[s] = py1[e];
        mx2[s] = px2[e]; my2[s] = py2[e];
        mbi[s] = pbi[e];
        mar[s] = (mx2[s] - mx1[s]) * (my2[s] - my1[s]);  // ref area expr
      } else {
        mx1[s] = 0; my1[s] = 0; mx2[s] = 0; my2[s] = 0; mar[s] = 0; mbi[s] = 0;
      }
    }
    ull km0 = mask_for(k);
    ull km1 = mask_for(k - 64);
    ull km2 = mask_for(k - 128);
    ull km3 = mask_for(k - 192);

    for (int r = 0; r < k - 1; r++) {
      ull cur = (r < 64) ? km0 : (r < 128) ? km1 : (r < 192) ? km2 : km3;
      if (!((cur >> (r & 63)) & 1ull)) continue;   // suppressed: skip cheap
      // broadcast box r via same-address LDS reads
      float X1 = px1[r], Y1 = py1[r], X2 = px2[r], Y2 = py2[r];
      float ar = (X2 - X1) * (Y2 - Y1);
      // slot 0
      {
        int e = lane;
        float iw = fminf(X2, mx2[0]) - fmaxf(X1, mx1[0]);
        float ih = fminf(Y2, my2[0]) - fmaxf(Y1, my1[0]);
        iw = fmaxf(iw, 0.0f); ih = fmaxf(ih, 0.0f);
        float inter = iw * ih;
        float iou = inter / (ar + mar[0] - inter + 1e-16f);
        km0 &= ~__ballot(iou >= 0.4f && e > r && e < k);
      }
      if (k > 64) {
        int e = 64 + lane;
        float iw = fminf(X2, mx2[1]) - fmaxf(X1, mx1[1]);
        float ih = fminf(Y2, my2[1]) - fmaxf(Y1, my1[1]);
        iw = fmaxf(iw, 0.0f); ih = fmaxf(ih, 0.0f);
        float inter = iw * ih;
        float iou = inter / (ar + mar[1] - inter + 1e-16f);
        km1 &= ~__ballot(iou >= 0.4f && e > r && e < k);
      }
      if (k > 128) {
        int e = 128 + lane;
        float iw = fminf(X2, mx2[2]) - fmaxf(X1, mx1[2]);
        float ih = fminf(Y2, my2[2]) - fmaxf(Y1, my1[2]);
        iw = fmaxf(iw, 0.0f); ih = fmaxf(ih, 0.0f);
        float inter = iw * ih;
        float iou = inter / (ar + mar[2] - inter + 1e-16f);
        km2 &= ~__ballot(iou >= 0.4f && e > r && e < k);
      }
      if (k > 192) {
        int e = 192 + lane;
        float iw = fminf(X2, mx2[3]) - fmaxf(X1, mx1[3]);
        float ih = fminf(Y2, my2[3]) - fmaxf(Y1, my1[3]);
        iw = fmaxf(iw, 0.0f); ih = fmaxf(ih, 0.0f);
        float inter = iw * ih;
        float iou = inter / (ar + mar[3] - inter + 1e-16f);
        km3 &= ~__ballot(iou >= 0.4f && e > r && e < k);
      }
    }

    // zero suppressed rows (kept rows already correct from prep)
    float4 z = make_float4(0.f, 0.f, 0.f, 0.f);
#pragma unroll
    for (int s = 0; s < 4; s++) {
      ull kms = (s == 0) ? km0 : (s == 1) ? km1 : (s == 2) ? km2 : km3;
      int e = s * 64 + lane;
      if (e < k && !((kms >> lane) & 1ull)) {
        float4* o = (float4*)(out + ((long)img * NBOX + mbi[s]) * 8);
        o[0] = z; o[1] = z;
      }
    }
  }
}

extern "C" void kernel_launch(void* const* d_in, const int* in_sizes, int n_in,
                              void* d_out, int out_size, void* d_ws, size_t ws_size,
                              hipStream_t stream) {
  const float* x = (const float*)d_in[0];
  float* out = (float*)d_out;
  int* vcls = (int*)d_ws;   // [BSZ*NBOX]

  prep_kernel<<<(BSZ * NBOX * 64) / 256, 256, 0, stream>>>(x, vcls, out);
  nms_kernel<<<BSZ * NCLS, 256, 0, stream>>>(vcls, out);
}

// Round 4
// 69.574 us; speedup vs baseline: 1.5333x; 1.0558x over previous
//
#include <hip/hip_runtime.h>

#define BSZ   2
#define NBOX  6300
#define NATTR 85
#define NCLS  80
#define CAP   256      // per-(img,class) cap; count ~ Binom(6300,1/160): mean 39, sd 6.3

typedef unsigned long long ull;

static __device__ __forceinline__ ull mask_for(int rem) {
  if (rem <= 0) return 0ull;
  if (rem >= 64) return ~0ull;
  return (1ull << rem) - 1ull;
}

// One wave per box. Lanes load the 85 attrs, butterfly-reduce max/argmax over
// class scores (attrs 5..84, first-index tiebreak = jnp.argmax). The wave
// writes its FINAL output row to d_out (real row if valid, zeros otherwise;
// each wave owns its 32-B row) and vcls[box] = valid ? cls : -1.
__global__ __launch_bounds__(256) void prep_kernel(
    const float* __restrict__ x,
    int* __restrict__ vcls,
    float* __restrict__ out) {
  int gid  = blockIdx.x * blockDim.x + threadIdx.x;
  int box  = gid >> 6;                 // grid exact: 12600 waves
  int lane = threadIdx.x & 63;

  const float* p = x + (long)box * NATTR;
  float r0 = p[lane];                                    // attrs 0..63
  float r1 = (lane < NATTR - 64) ? p[64 + lane] : -1.0f; // attrs 64..84

  float c0 = (lane >= 5) ? r0 : -1.0f;
  float v; int vi;
  if (r1 > c0) { v = r1; vi = 64 + lane; }   // equal -> keep lower index c0
  else         { v = c0; vi = lane; }

  for (int off = 32; off > 0; off >>= 1) {   // butterfly max-argmax
    float ov = __shfl_xor(v, off);
    int   oi = __shfl_xor(vi, off);
    if (ov > v || (ov == v && oi < vi)) { v = ov; vi = oi; }
  }

  float cx  = __shfl(r0, 0), cy = __shfl(r0, 1);
  float w   = __shfl(r0, 2), h  = __shfl(r0, 3);
  float obj = __shfl(r0, 4);
  bool valid = (obj > 0.5f) && (v > 0.3f);
  int  img   = box >= NBOX ? 1 : 0;
  int  cls   = vi - 5;

  if (lane == 0) {
    vcls[box] = valid ? cls : -1;
    float4 a, b;
    if (valid) {
      float hw = w * 0.5f, hh = h * 0.5f;    // exact halving; fma-safe
      a = make_float4((float)img, cx - hw, cy - hh, cx + hw);
      b = make_float4(cy + hh, obj, v, (float)cls);
    } else {
      a = make_float4(0.f, 0.f, 0.f, 0.f);
      b = a;
    }
    float4* o = (float4*)(out + (long)box * 8);
    o[0] = a; o[1] = b;
  }
}

// One 256-thread block (4 waves) per (image, class). Per-class greedy NMS is
// exactly equivalent to the ref's global greedy loop (suppression requires
// same_cls; invalid boxes never act). Kept rows already final in d_out; this
// kernel only ZEROES suppressed rows. Fast path (k<=64, always on this data):
// whole NMS in wave-0 registers via shfl/ds_permute/ballot — no LDS in the
// serial chains. Generic LDS path retained for k>64.
__global__ __launch_bounds__(256) void nms_kernel(
    const int* __restrict__ vcls,
    float* out) {
  __shared__ int   wlist[4][CAP];
  __shared__ int   wcnt[4];
  __shared__ int   sbi[CAP];
  // fallback-only arrays (k > 64)
  __shared__ float ssc[CAP];
  __shared__ float px1[CAP], py1[CAP], px2[CAP], py2[CAP];
  __shared__ int   pbi[CAP];

  int bc   = blockIdx.x;
  int img  = bc / NCLS;
  int cls  = bc - img * NCLS;
  int t    = threadIdx.x;
  int lane = t & 63;
  int w    = t >> 6;
  const int* v = vcls + img * NBOX;

  // ---- Phase A: parallel class scan (4 waves x 25 iters over 6300) ----
  int base = w * 1600;                 // 4*1600 = 6400 >= 6300
  int vals[25];
#pragma unroll
  for (int i = 0; i < 25; i++) {
    int idx = base + i * 64 + lane;
    vals[i] = (idx < NBOX) ? v[idx] : -1;
  }
  int cnt = 0;
#pragma unroll
  for (int i = 0; i < 25; i++) {
    bool match = (vals[i] == cls);
    ull  m = __ballot(match);
    if (match) {
      int pos = cnt + __popcll(m & ((1ull << lane) - 1ull));
      if (pos < CAP) wlist[w][pos] = base + i * 64 + lane;
    }
    cnt += __popcll(m);
  }
  if (lane == 0) wcnt[w] = cnt < CAP ? cnt : CAP;
  __syncthreads();

  int off = 0, total = 0;
  for (int j = 0; j < 4; j++) {
    int c = wcnt[j];
    if (j < w) off += c;
    total += c;
  }
  int k = total < CAP ? total : CAP;
  if (k == 0) return;                  // uniform

  for (int j = lane; j < wcnt[w]; j += 64) {
    int d = off + j;
    if (d < CAP) sbi[d] = wlist[w][j];  // ascending box-index order
  }
  __syncthreads();

  if (k <= 64) {
    // ================== register fast path (wave 0 only) ==================
    if (w == 0) {
      int j = lane;
      float x1 = 0.f, y1 = 0.f, x2 = 0.f, y2 = 0.f, sc = 0.f;
      int bi = 0;
      if (j < k) {
        bi = sbi[j];
        const float4* o = (const float4*)(out + ((long)img * NBOX + bi) * 8);
        float4 a = o[0], b = o[1];
        x1 = a.y; y1 = a.z; x2 = a.w; y2 = b.x; sc = b.y;
      }
      // rank = stable argsort(-score, tiebreak: box index asc).
      // All 64 lanes run the loop (no divergence -> shfl well-defined);
      // j>=k lanes get identity rank j (>= k, no collision: sc=0 there).
      int rank = 0;
      for (int i = 0; i < k; i++) {
        float si  = __shfl(sc, i);
        int   bii = __shfl(bi, i);
        rank += (si > sc) || (si == sc && bii < bi);
      }
      if (j >= k) rank = j;

      // scatter to rank order: after this, lane index == rank.
      int r4 = rank << 2;
      x1 = __int_as_float(__builtin_amdgcn_ds_permute(r4, __float_as_int(x1)));
      y1 = __int_as_float(__builtin_amdgcn_ds_permute(r4, __float_as_int(y1)));
      x2 = __int_as_float(__builtin_amdgcn_ds_permute(r4, __float_as_int(x2)));
      y2 = __int_as_float(__builtin_amdgcn_ds_permute(r4, __float_as_int(y2)));
      bi = __builtin_amdgcn_ds_permute(r4, bi);

      float ar = (x2 - x1) * (y2 - y1);   // ref area expression

      // greedy: kept rank r suppresses later ranks with IoU >= 0.4
      ull keep = mask_for(k);
      for (int r = 0; r < k - 1; r++) {
        if (!((keep >> r) & 1ull)) continue;   // uniform skip
        float X1 = __shfl(x1, r), Y1 = __shfl(y1, r);
        float X2 = __shfl(x2, r), Y2 = __shfl(y2, r);
        float AR = __shfl(ar, r);
        float iw = fminf(X2, x2) - fmaxf(X1, x1);
        float ih = fminf(Y2, y2) - fmaxf(Y1, y1);
        iw = fmaxf(iw, 0.0f); ih = fmaxf(ih, 0.0f);
        float inter = iw * ih;
        float iou = inter / (AR + ar - inter + 1e-16f);  // ref assoc + eps
        keep &= ~__ballot(iou >= 0.4f && lane > r);
      }

      // zero only the suppressed rows (kept rows already final from prep)
      if (lane < k && !((keep >> lane) & 1ull)) {
        float4 z = make_float4(0.f, 0.f, 0.f, 0.f);
        float4* o = (float4*)(out + ((long)img * NBOX + bi) * 8);
        o[0] = z; o[1] = z;
      }
    }
    return;
  }

  // ====================== generic LDS fallback (k > 64) ======================
  float bx1 = 0, by1 = 0, bx2 = 0, by2 = 0, bobj = 0;
  int   bidx = 0;
  if (t < k) {
    bidx = sbi[t];
    const float4* o = (const float4*)(out + ((long)img * NBOX + bidx) * 8);
    float4 a = o[0], b = o[1];
    bx1 = a.y; by1 = a.z; bx2 = a.w; by2 = b.x; bobj = b.y;
    ssc[t] = bobj;
  }
  __syncthreads();

  if (t < k) {
    int rank = 0;
    for (int j = 0; j < k; j++) {
      float sj = ssc[j];
      rank += (sj > bobj) || (sj == bobj && sbi[j] < bidx);
    }
    px1[rank] = bx1; py1[rank] = by1;
    px2[rank] = bx2; py2[rank] = by2;
    pbi[rank] = bidx;
  }
  __syncthreads();

  if (w == 0) {
    float mx1[4], my1[4], mx2[4], my2[4], mar[4];
    int   mbi[4];
#pragma unroll
    for (int s = 0; s < 4; s++) {
      int e = s * 64 + lane;
      if (e < k) {
        mx1[s] = px1[e]; my1[s] = py1[e];
        mx2[s] = px2[e]; my2[s] = py2[e];
        mbi[s] = pbi[e];
        mar[s] = (mx2[s] - mx1[s]) * (my2[s] - my1[s]);
      } else {
        mx1[s] = 0; my1[s] = 0; mx2[s] = 0; my2[s] = 0; mar[s] = 0; mbi[s] = 0;
      }
    }
    ull km0 = mask_for(k);
    ull km1 = mask_for(k - 64);
    ull km2 = mask_for(k - 128);
    ull km3 = mask_for(k - 192);

    for (int r = 0; r < k - 1; r++) {
      ull cur = (r < 64) ? km0 : (r < 128) ? km1 : (r < 192) ? km2 : km3;
      if (!((cur >> (r & 63)) & 1ull)) continue;
      float X1 = px1[r], Y1 = py1[r], X2 = px2[r], Y2 = py2[r];
      float ar = (X2 - X1) * (Y2 - Y1);
      {
        int e = lane;
        float iw = fminf(X2, mx2[0]) - fmaxf(X1, mx1[0]);
        float ih = fminf(Y2, my2[0]) - fmaxf(Y1, my1[0]);
        iw = fmaxf(iw, 0.0f); ih = fmaxf(ih, 0.0f);
        float inter = iw * ih;
        float iou = inter / (ar + mar[0] - inter + 1e-16f);
        km0 &= ~__ballot(iou >= 0.4f && e > r && e < k);
      }
      if (k > 64) {
        int e = 64 + lane;
        float iw = fminf(X2, mx2[1]) - fmaxf(X1, mx1[1]);
        float ih = fminf(Y2, my2[1]) - fmaxf(Y1, my1[1]);
        iw = fmaxf(iw, 0.0f); ih = fmaxf(ih, 0.0f);
        float inter = iw * ih;
        float iou = inter / (ar + mar[1] - inter + 1e-16f);
        km1 &= ~__ballot(iou >= 0.4f && e > r && e < k);
      }
      if (k > 128) {
        int e = 128 + lane;
        float iw = fminf(X2, mx2[2]) - fmaxf(X1, mx1[2]);
        float ih = fminf(Y2, my2[2]) - fmaxf(Y1, my1[2]);
        iw = fmaxf(iw, 0.0f); ih = fmaxf(ih, 0.0f);
        float inter = iw * ih;
        float iou = inter / (ar + mar[2] - inter + 1e-16f);
        km2 &= ~__ballot(iou >= 0.4f && e > r && e < k);
      }
      if (k > 192) {
        int e = 192 + lane;
        float iw = fminf(X2, mx2[3]) - fmaxf(X1, mx1[3]);
        float ih = fminf(Y2, my2[3]) - fmaxf(Y1, my1[3]);
        iw = fmaxf(iw, 0.0f); ih = fmaxf(ih, 0.0f);
        float inter = iw * ih;
        float iou = inter / (ar + mar[3] - inter + 1e-16f);
        km3 &= ~__ballot(iou >= 0.4f && e > r && e < k);
      }
    }

    float4 z = make_float4(0.f, 0.f, 0.f, 0.f);
#pragma unroll
    for (int s = 0; s < 4; s++) {
      ull kms = (s == 0) ? km0 : (s == 1) ? km1 : (s == 2) ? km2 : km3;
      int e = s * 64 + lane;
      if (e < k && !((kms >> lane) & 1ull)) {
        float4* o = (float4*)(out + ((long)img * NBOX + mbi[s]) * 8);
        o[0] = z; o[1] = z;
      }
    }
  }
}

extern "C" void kernel_launch(void* const* d_in, const int* in_sizes, int n_in,
                              void* d_out, int out_size, void* d_ws, size_t ws_size,
                              hipStream_t stream) {
  const float* x = (const float*)d_in[0];
  float* out = (float*)d_out;
  int* vcls = (int*)d_ws;   // [BSZ*NBOX]

  prep_kernel<<<(BSZ * NBOX * 64) / 256, 256, 0, stream>>>(x, vcls, out);
  nms_kernel<<<BSZ * NCLS, 256, 0, stream>>>(vcls, out);
}